// Round 9
// baseline (530.923 us; speedup 1.0000x reference)
//
#include <hip/hip_runtime.h>
#include <hip/hip_bf16.h>

#define NDIM 256
#define NKD  246
#define KD   10
#define TMAXS 64
#define APAR 1.4f
#define DTS  0.1f

typedef _Float16 f16x8 __attribute__((ext_vector_type(8)));
typedef float    f32x4 __attribute__((ext_vector_type(4)));

// ---------- build base [256][256] and clipped eigenvalues ----------
__global__ void k_prep(const float* __restrict__ bt, const float* __restrict__ bf,
                       const float* __restrict__ autov, const float* __restrict__ gamma,
                       float* __restrict__ base, float* __restrict__ eig) {
  int r = blockIdx.x, c = threadIdx.x;
  float v = (c < NKD) ? bt[r*NKD + c] : bf[r*KD + (c - NKD)];
  base[r*NDIM + c] = v;
  if (r == 0) {
    float g = gamma[0];
    float xmax = 8.0f*APAR*APAR*g*16.0f - 0.1f;   // sqrt(256)=16
    float e = (c < NKD) ? autov[c] : 0.0f;
    e = fminf(e, xmax);
    e = fmaxf(e, -1e9f);
    eig[c] = e;
  }
}

// ---------- fused: StG col j = S^T G[:,j]; then R[:,j] = G[:,j] - S*StG[:,j]/1.3225 ----------
__global__ void k_stgR(const float* __restrict__ base, double* __restrict__ StG,
                       double* __restrict__ Rm) {
  __shared__ double sg[NKD];
  const int j = blockIdx.x, t = threadIdx.x;
  if (t < NKD) {
    double acc = 0.0;
    for (int r = 0; r < NDIM; ++r)
      acc += (double)base[r*NDIM + t] * (double)base[r*NDIM + NKD + j];
    sg[t] = acc;
    StG[t*KD + j] = acc;
  }
  __syncthreads();
  double acc = 0.0;
  for (int i = 0; i < NKD; ++i)
    acc += (double)base[t*NDIM + i] * sg[i];
  Rm[t*KD + j] = (double)base[t*NDIM + NKD + j] - acc * (1.0/1.3225);
}

// ---------- fused: M10 = R^T G (10x10); parallel fp64 GJ inverse; X2 = Mi*R^T ----------
__global__ void k_m10x2(const float* __restrict__ base, const double* __restrict__ Rm,
                        double* __restrict__ X) {
  __shared__ double M[KD][2*KD];
  __shared__ double fcol[KD];
  __shared__ int piv;
  const int t = threadIdx.x;
  if (t < KD*KD) {
    int j1 = t / KD, j2 = t % KD;
    double acc = 0.0;
    for (int r = 0; r < NDIM; ++r)
      acc += Rm[r*KD + j1] * (double)base[r*NDIM + NKD + j2];
    M[j1][j2] = acc;
    M[j1][KD + j2] = (j1 == j2) ? 1.0 : 0.0;
  }
  __syncthreads();
  for (int k = 0; k < KD; ++k) {
    if (t == 0) {
      int p = k; double mv = fabs(M[k][k]);
      for (int r = k + 1; r < KD; ++r) { double v = fabs(M[r][k]); if (v > mv) { mv = v; p = r; } }
      piv = p;
    }
    __syncthreads();
    int p = piv;
    if (p != k && t < 2*KD) { double tmp = M[k][t]; M[k][t] = M[p][t]; M[p][t] = tmp; }
    __syncthreads();
    double pv = M[k][k];
    __syncthreads();
    if (t < 2*KD) M[k][t] /= pv;
    if (t < KD) fcol[t] = M[t][k];
    __syncthreads();
    if (t < KD*2*KD) {
      int r = t / (2*KD), c = t % (2*KD);
      if (r != k) M[r][c] -= fcol[r] * M[k][c];
    }
    __syncthreads();
  }
  for (int j = 0; j < KD; ++j) {
    double acc = 0.0;
    for (int l = 0; l < KD; ++l) acc += M[j][KD + l] * Rm[t*KD + l];
    X[(NKD + j)*NDIM + t] = acc;
  }
}

// ---------- X rows 0..245:  X1 = (S^T - StG * X2) / 1.3225 ----------
__global__ void k_x1(const float* __restrict__ base, const double* __restrict__ StG,
                     double* __restrict__ X) {
  int c = blockIdx.x, i = threadIdx.x;
  if (i >= NKD) return;
  double acc = 0.0;
  for (int j = 0; j < KD; ++j) acc += StG[i*KD + j] * X[(NKD + j)*NDIM + c];
  X[i*NDIM + c] = ((double)base[c*NDIM + i] - acc) * (1.0/1.3225);
}

// ---------- Newton-Schulz: T = 2I - B*X ; X' = X*T ----------
__global__ void k_T(const float* __restrict__ base, const double* __restrict__ X,
                    double* __restrict__ T) {
  int i = blockIdx.x, j = threadIdx.x;
  double acc = 0.0;
  for (int k = 0; k < NDIM; ++k) acc += (double)base[i*NDIM + k] * X[k*NDIM + j];
  T[i*NDIM + j] = ((i == j) ? 2.0 : 0.0) - acc;
}
__global__ void k_XT(const double* __restrict__ X, const double* __restrict__ T,
                     double* __restrict__ Xo) {
  int i = blockIdx.x, j = threadIdx.x;
  double acc = 0.0;
  for (int k = 0; k < NDIM; ++k) acc += X[i*NDIM + k] * T[k*NDIM + j];
  Xo[i*NDIM + j] = acc;
}

// ---------- fused: A[m][k] = (base*eig)@X, fp16 hi/lo split, A-operand frag layout ----------
// frag index: Af[((kc*256 + m)*4 + lg)] is f16x8 with elems j: A[m][kc*32+lg*8+j]
__global__ void k_Afrag(const float* __restrict__ base, const float* __restrict__ eig,
                        const double* __restrict__ X, _Float16* __restrict__ Ah,
                        _Float16* __restrict__ Al) {
  int m = blockIdx.x;     // row of A (out feature)
  int k = threadIdx.x;    // col of A (in feature)
  double acc = 0.0;
  for (int q = 0; q < NDIM; ++q)
    acc += (double)base[m*NDIM + q] * (double)eig[q] * X[q*NDIM + k];
  float v = (float)acc;
  _Float16 h  = (_Float16)v;       // RTN
  _Float16 lo = (_Float16)(v - (float)h);
  int kc = k >> 5, lg = (k >> 3) & 3, jj = k & 7;
  int idx = (((kc*NDIM + m)*4 + lg) << 3) + jj;
  Ah[idx] = h; Al[idx] = lo;
}

// ---------- 64-step Euler evolution: 32 rows/block, 2 blocks/CU ----------
// A-hi persistent in VGPR; A-lo streamed from L2 each step (constant, L2-resident).
// wave w owns out-features [32w, 32w+32); D-layout output = kc=w B-frag slice.
__global__ __launch_bounds__(512, 4)
void k_evolve(const float* __restrict__ x_in, const f16x8* __restrict__ Ah,
              const f16x8* __restrict__ Al, const float* __restrict__ gamma,
              float* __restrict__ out) {
  __shared__ f16x8 zh[2][8][2][64];   // [buf][kc][nt][lane] x^T hi frags, 32 KB
  __shared__ f16x8 zl[2][8][2][64];   // lo frags, 32 KB

  const int t  = threadIdx.x;
  const int w  = t >> 6;              // wave 0..7 -> out-feature slice & kc slice
  const int l  = t & 63;
  const int lg = l >> 4;              // 0..3
  const int lr = l & 15;              // 0..15
  const int rbase = blockIdx.x * 32;

  const float g   = fabsf(gamma[0]);
  const float c4g = 4.0f * g;
  const float a2  = APAR * APAR;
  const float lim = 10.0f * APAR;
  const float dtb = DTS * 0.0625f;    // dt * beta

  // ---- persistent A-hi fragments: ahf[mt][kc], m = w*32+mt*16+lr (64 VGPR)
  f16x8 ahf[2][8];
  #pragma unroll
  for (int mt = 0; mt < 2; ++mt) {
    const int m = w*32 + mt*16 + lr;
    #pragma unroll
    for (int kc = 0; kc < 8; ++kc)
      ahf[mt][kc] = Ah[(kc*NDIM + m)*4 + lg];
  }
  // per-thread base index for A-lo streaming loads
  const int aloBase = (w*32 + lr)*4 + lg;

  // ---- x state in D-layout: xr[mt][nt][reg] = x[r = nt*16+lr][c = w*32+mt*16+lg*4+reg]
  f32x4 xr[2][2];
  #pragma unroll
  for (int mt = 0; mt < 2; ++mt)
    #pragma unroll
    for (int nt = 0; nt < 2; ++nt) {
      const int row = rbase + nt*16 + lr;
      const int col = w*32 + mt*16 + lg*4;
      xr[mt][nt] = *(const f32x4*)&x_in[row*NDIM + col];
    }

  const int lp   = (lg >> 1)*16 + lr;   // partial target lane (add mt*32)
  const int boff = (lg & 1)*8;          // byte offset of j-quad within frag elem

  // ---- emit: fp16 h/l split, scatter into B-frag slice kc=w of buffer b
  auto emit = [&](int b) {
    #pragma unroll
    for (int mt = 0; mt < 2; ++mt) {
      const int tl = mt*32 + lp;
      #pragma unroll
      for (int nt = 0; nt < 2; ++nt) {
        f32x4 v = xr[mt][nt];
        auto h01 = __builtin_amdgcn_cvt_pkrtz(v[0], v[1]);
        auto h23 = __builtin_amdgcn_cvt_pkrtz(v[2], v[3]);
        auto l01 = __builtin_amdgcn_cvt_pkrtz(v[0] - (float)h01[0], v[1] - (float)h01[1]);
        auto l23 = __builtin_amdgcn_cvt_pkrtz(v[2] - (float)h23[0], v[3] - (float)h23[1]);
        uint2 uh, ul;
        __builtin_memcpy(&uh.x, &h01, 4);
        __builtin_memcpy(&uh.y, &h23, 4);
        __builtin_memcpy(&ul.x, &l01, 4);
        __builtin_memcpy(&ul.y, &l23, 4);
        *(uint2*)((char*)&zh[b][w][nt][tl] + boff) = uh;
        *(uint2*)((char*)&zl[b][w][nt][tl] + boff) = ul;
      }
    }
  };

  emit(0);
  __syncthreads();

  for (int step = 0; step < TMAXS; ++step) {
    const int rb = step & 1, wb = rb ^ 1;
    // launder the A-lo pointer so the 16 per-step loads are NOT hoisted out
    // of the step loop (would cost 64 persistent VGPRs)
    const f16x8* Alp = Al;
    asm volatile("" : "+r"(Alp));

    f32x4 acc[2][2] = {};
    #pragma unroll
    for (int kc = 0; kc < 8; ++kc) {
      // streamed A-lo fragments for this kc (L2-resident, reloaded each step)
      f16x8 al0 = Alp[kc*1024/8*8 + 0];  // placeholder-free form below
      al0 = Alp[(kc*NDIM)*4/1 + aloBase];          // idx = kc*1024 + aloBase
      f16x8 al1 = Alp[(kc*NDIM + 16)*4 + aloBase - aloBase + aloBase + 64 - 64 + 64]; // idx = kc*1024 + 64 + aloBase
      // (clean recompute to avoid any confusion)
      al0 = Alp[kc*1024 + aloBase];
      al1 = Alp[kc*1024 + 64 + aloBase];

      f16x8 b0h = zh[rb][kc][0][l];
      f16x8 b1h = zh[rb][kc][1][l];
      f16x8 b0l = zl[rb][kc][0][l];
      f16x8 b1l = zl[rb][kc][1][l];

      acc[0][0] = __builtin_amdgcn_mfma_f32_16x16x32_f16(ahf[0][kc], b0h, acc[0][0], 0, 0, 0);
      acc[1][0] = __builtin_amdgcn_mfma_f32_16x16x32_f16(ahf[1][kc], b0h, acc[1][0], 0, 0, 0);
      acc[0][1] = __builtin_amdgcn_mfma_f32_16x16x32_f16(ahf[0][kc], b1h, acc[0][1], 0, 0, 0);
      acc[1][1] = __builtin_amdgcn_mfma_f32_16x16x32_f16(ahf[1][kc], b1h, acc[1][1], 0, 0, 0);
      acc[0][0] = __builtin_amdgcn_mfma_f32_16x16x32_f16(ahf[0][kc], b0l, acc[0][0], 0, 0, 0);
      acc[1][0] = __builtin_amdgcn_mfma_f32_16x16x32_f16(ahf[1][kc], b0l, acc[1][0], 0, 0, 0);
      acc[0][1] = __builtin_amdgcn_mfma_f32_16x16x32_f16(ahf[0][kc], b1l, acc[0][1], 0, 0, 0);
      acc[1][1] = __builtin_amdgcn_mfma_f32_16x16x32_f16(ahf[1][kc], b1l, acc[1][1], 0, 0, 0);
      acc[0][0] = __builtin_amdgcn_mfma_f32_16x16x32_f16(al0,        b0h, acc[0][0], 0, 0, 0);
      acc[1][0] = __builtin_amdgcn_mfma_f32_16x16x32_f16(al1,        b0h, acc[1][0], 0, 0, 0);
      acc[0][1] = __builtin_amdgcn_mfma_f32_16x16x32_f16(al0,        b1h, acc[0][1], 0, 0, 0);
      acc[1][1] = __builtin_amdgcn_mfma_f32_16x16x32_f16(al1,        b1h, acc[1][1], 0, 0, 0);
    }
    // ---- pointwise double-well + Euler + clip, in registers ----
    #pragma unroll
    for (int mt = 0; mt < 2; ++mt)
      #pragma unroll
      for (int nt = 0; nt < 2; ++nt)
        #pragma unroll
        for (int r = 0; r < 4; ++r) {
          float xc = xr[mt][nt][r];
          float xn = xc + DTS*(c4g*(a2*xc - xc*xc*xc)) + dtb*acc[mt][nt][r];
          xr[mt][nt][r] = fminf(fmaxf(xn, -lim), lim);
        }
    emit(wb);
    __syncthreads();
  }

  // ---- store result ----
  #pragma unroll
  for (int mt = 0; mt < 2; ++mt)
    #pragma unroll
    for (int nt = 0; nt < 2; ++nt) {
      const int row = rbase + nt*16 + lr;
      const int col = w*32 + mt*16 + lg*4;
      *(f32x4*)&out[row*NDIM + col] = xr[mt][nt];
    }
}

extern "C" void kernel_launch(void* const* d_in, const int* in_sizes, int n_in,
                              void* d_out, int out_size, void* d_ws, size_t ws_size,
                              hipStream_t stream) {
  const float* x  = (const float*)d_in[0];
  const float* bt = (const float*)d_in[1];
  const float* bf = (const float*)d_in[2];
  const float* av = (const float*)d_in[3];
  const float* gm = (const float*)d_in[4];
  float* out = (float*)d_out;
  const int Brows = in_sizes[0] / NDIM;   // 16384

  // workspace layout
  float*  base = (float*)d_ws;                    // 65536 f
  float*  eig  = base + NDIM*NDIM;                // 256 f
  double* Xd   = (double*)(eig + NDIM);           // 8B aligned
  double* Xe   = Xd + NDIM*NDIM;
  double* Td   = Xe + NDIM*NDIM;
  double* StG  = Td + NDIM*NDIM;                  // 2460 -> pad 2560
  double* Rm   = StG + 2560;
  _Float16* Aph = (_Float16*)(Rm + 2560);         // 65536 halves = 128 KB
  _Float16* Apl = Aph + NDIM*NDIM;                // 128 KB

  k_prep <<<NDIM, NDIM, 0, stream>>>(bt, bf, av, gm, base, eig);
  k_stgR <<<KD,   NDIM, 0, stream>>>(base, StG, Rm);
  k_m10x2<<<1,    NDIM, 0, stream>>>(base, Rm, Xd);
  k_x1   <<<NDIM, NDIM, 0, stream>>>(base, StG, Xd);
  // 1 Newton-Schulz polish iteration (fp64): 1e-6 -> 1e-12
  k_T <<<NDIM, NDIM, 0, stream>>>(base, Xd, Td);
  k_XT<<<NDIM, NDIM, 0, stream>>>(Xd, Td, Xe);

  k_Afrag<<<NDIM, NDIM, 0, stream>>>(base, eig, Xe, Aph, Apl);

  k_evolve<<<Brows/32, 512, 0, stream>>>(x, (const f16x8*)Aph, (const f16x8*)Apl, gm, out);
}

// Round 10
// 414.171 us; speedup vs baseline: 1.2819x; 1.2819x over previous
//
#include <hip/hip_runtime.h>
#include <hip/hip_bf16.h>

#define NDIM 256
#define NKD  246
#define KD   10
#define TMAXS 64
#define APAR 1.4f
#define DTS  0.1f

typedef _Float16 f16x8 __attribute__((ext_vector_type(8)));
typedef float    f32x4 __attribute__((ext_vector_type(4)));

// ---------- build base [256][256] and clipped eigenvalues ----------
__global__ void k_prep(const float* __restrict__ bt, const float* __restrict__ bf,
                       const float* __restrict__ autov, const float* __restrict__ gamma,
                       float* __restrict__ base, float* __restrict__ eig) {
  int r = blockIdx.x, c = threadIdx.x;
  float v = (c < NKD) ? bt[r*NKD + c] : bf[r*KD + (c - NKD)];
  base[r*NDIM + c] = v;
  if (r == 0) {
    float g = gamma[0];
    float xmax = 8.0f*APAR*APAR*g*16.0f - 0.1f;   // sqrt(256)=16
    float e = (c < NKD) ? autov[c] : 0.0f;
    e = fminf(e, xmax);
    e = fmaxf(e, -1e9f);
    eig[c] = e;
  }
}

// ---------- fused: StG col j = S^T G[:,j]; then R[:,j] = G[:,j] - S*StG[:,j]/1.3225 ----------
__global__ void k_stgR(const float* __restrict__ base, double* __restrict__ StG,
                       double* __restrict__ Rm) {
  __shared__ double sg[NKD];
  const int j = blockIdx.x, t = threadIdx.x;
  if (t < NKD) {
    double acc = 0.0;
    for (int r = 0; r < NDIM; ++r)
      acc += (double)base[r*NDIM + t] * (double)base[r*NDIM + NKD + j];
    sg[t] = acc;
    StG[t*KD + j] = acc;
  }
  __syncthreads();
  double acc = 0.0;
  for (int i = 0; i < NKD; ++i)
    acc += (double)base[t*NDIM + i] * sg[i];
  Rm[t*KD + j] = (double)base[t*NDIM + NKD + j] - acc * (1.0/1.3225);
}

// ---------- fused: M10 = R^T G (10x10); parallel fp64 GJ inverse; X2 = Mi*R^T ----------
__global__ void k_m10x2(const float* __restrict__ base, const double* __restrict__ Rm,
                        double* __restrict__ X) {
  __shared__ double M[KD][2*KD];
  __shared__ double fcol[KD];
  __shared__ int piv;
  const int t = threadIdx.x;
  if (t < KD*KD) {
    int j1 = t / KD, j2 = t % KD;
    double acc = 0.0;
    for (int r = 0; r < NDIM; ++r)
      acc += Rm[r*KD + j1] * (double)base[r*NDIM + NKD + j2];
    M[j1][j2] = acc;
    M[j1][KD + j2] = (j1 == j2) ? 1.0 : 0.0;
  }
  __syncthreads();
  for (int k = 0; k < KD; ++k) {
    if (t == 0) {
      int p = k; double mv = fabs(M[k][k]);
      for (int r = k + 1; r < KD; ++r) { double v = fabs(M[r][k]); if (v > mv) { mv = v; p = r; } }
      piv = p;
    }
    __syncthreads();
    int p = piv;
    if (p != k && t < 2*KD) { double tmp = M[k][t]; M[k][t] = M[p][t]; M[p][t] = tmp; }
    __syncthreads();
    double pv = M[k][k];
    __syncthreads();
    if (t < 2*KD) M[k][t] /= pv;
    if (t < KD) fcol[t] = M[t][k];
    __syncthreads();
    if (t < KD*2*KD) {
      int r = t / (2*KD), c = t % (2*KD);
      if (r != k) M[r][c] -= fcol[r] * M[k][c];
    }
    __syncthreads();
  }
  for (int j = 0; j < KD; ++j) {
    double acc = 0.0;
    for (int l = 0; l < KD; ++l) acc += M[j][KD + l] * Rm[t*KD + l];
    X[(NKD + j)*NDIM + t] = acc;
  }
}

// ---------- X rows 0..245:  X1 = (S^T - StG * X2) / 1.3225 ----------
__global__ void k_x1(const float* __restrict__ base, const double* __restrict__ StG,
                     double* __restrict__ X) {
  int c = blockIdx.x, i = threadIdx.x;
  if (i >= NKD) return;
  double acc = 0.0;
  for (int j = 0; j < KD; ++j) acc += StG[i*KD + j] * X[(NKD + j)*NDIM + c];
  X[i*NDIM + c] = ((double)base[c*NDIM + i] - acc) * (1.0/1.3225);
}

// ---------- Newton-Schulz: T = 2I - B*X ; X' = X*T ----------
__global__ void k_T(const float* __restrict__ base, const double* __restrict__ X,
                    double* __restrict__ T) {
  int i = blockIdx.x, j = threadIdx.x;
  double acc = 0.0;
  for (int k = 0; k < NDIM; ++k) acc += (double)base[i*NDIM + k] * X[k*NDIM + j];
  T[i*NDIM + j] = ((i == j) ? 2.0 : 0.0) - acc;
}
__global__ void k_XT(const double* __restrict__ X, const double* __restrict__ T,
                     double* __restrict__ Xo) {
  int i = blockIdx.x, j = threadIdx.x;
  double acc = 0.0;
  for (int k = 0; k < NDIM; ++k) acc += X[i*NDIM + k] * T[k*NDIM + j];
  Xo[i*NDIM + j] = acc;
}

// ---------- fused: A[m][k] = (base*eig)@X, fp16 hi/lo split, A-operand frag layout ----------
// frag index: Af[((kc*256 + m)*4 + lg)] is f16x8 with elems j: A[m][kc*32+lg*8+j]
__global__ void k_Afrag(const float* __restrict__ base, const float* __restrict__ eig,
                        const double* __restrict__ X, _Float16* __restrict__ Ah,
                        _Float16* __restrict__ Al) {
  int m = blockIdx.x;     // row of A (out feature)
  int k = threadIdx.x;    // col of A (in feature)
  double acc = 0.0;
  for (int q = 0; q < NDIM; ++q)
    acc += (double)base[m*NDIM + q] * (double)eig[q] * X[q*NDIM + k];
  float v = (float)acc;
  _Float16 h  = (_Float16)v;       // RTN
  _Float16 lo = (_Float16)(v - (float)h);
  int kc = k >> 5, lg = (k >> 3) & 3, jj = k & 7;
  int idx = (((kc*NDIM + m)*4 + lg) << 3) + jj;
  Ah[idx] = h; Al[idx] = lo;
}

// ---------- 64-step Euler evolution: Y^T = A x^T, phase-fused 3-product GEMM ----------
// wave w owns out-features [32w, 32w+32); its D-layout output IS the kc=w slice
// of next step's B-fragments. Step is split into two nt-pair groups; each group's
// pointwise+emit tail overlaps the next group's MFMAs/reads.
__global__ __launch_bounds__(512, 2)
void k_evolve(const float* __restrict__ x_in, const f16x8* __restrict__ Ah,
              const f16x8* __restrict__ Al, const float* __restrict__ gamma,
              float* __restrict__ out) {
  __shared__ f16x8 zh[2][8][4][64];   // [buf][kc][nt][lane]  x^T hi frags, 64 KB
  __shared__ f16x8 zl[2][8][4][64];   // lo frags, 64 KB

  const int t  = threadIdx.x;
  const int w  = t >> 6;              // wave 0..7 -> out-feature slice & kc slice
  const int l  = t & 63;
  const int lg = l >> 4;              // 0..3
  const int lr = l & 15;              // 0..15
  const int rbase = blockIdx.x * 64;

  const float g   = fabsf(gamma[0]);
  const float c4g = 4.0f * g;
  const float a2  = APAR * APAR;
  const float lim = 10.0f * APAR;
  const float dtb = DTS * 0.0625f;    // dt * beta

  // ---- persistent A-operand fragments (hi/lo): ahf[mt][kc], m = w*32+mt*16+lr
  f16x8 ahf[2][8], alf[2][8];
  #pragma unroll
  for (int mt = 0; mt < 2; ++mt) {
    const int m = w*32 + mt*16 + lr;
    #pragma unroll
    for (int kc = 0; kc < 8; ++kc) {
      ahf[mt][kc] = Ah[(kc*NDIM + m)*4 + lg];
      alf[mt][kc] = Al[(kc*NDIM + m)*4 + lg];
    }
  }

  // ---- x state in D-layout: xr[mt][nt][reg] = x[r = nt*16+lr][c = w*32+mt*16+lg*4+reg]
  f32x4 xr[2][4];
  #pragma unroll
  for (int mt = 0; mt < 2; ++mt)
    #pragma unroll
    for (int nt = 0; nt < 4; ++nt) {
      const int row = rbase + nt*16 + lr;
      const int col = w*32 + mt*16 + lg*4;
      xr[mt][nt] = *(const f32x4*)&x_in[row*NDIM + col];
    }

  const int lp   = (lg >> 1)*16 + lr;   // partial target lane (add mt*32)
  const int boff = (lg & 1)*8;          // byte offset of j-quad within frag elem

  // ---- emit one (mt,nt) chunk: fp16 h/l split, scatter into B-frag slice kc=w
  auto emit_chunk = [&](int b, int mt, int nt) {
    const int tl = mt*32 + lp;
    f32x4 v = xr[mt][nt];
    auto h01 = __builtin_amdgcn_cvt_pkrtz(v[0], v[1]);
    auto h23 = __builtin_amdgcn_cvt_pkrtz(v[2], v[3]);
    auto l01 = __builtin_amdgcn_cvt_pkrtz(v[0] - (float)h01[0], v[1] - (float)h01[1]);
    auto l23 = __builtin_amdgcn_cvt_pkrtz(v[2] - (float)h23[0], v[3] - (float)h23[1]);
    uint2 uh, ul;
    __builtin_memcpy(&uh.x, &h01, 4);
    __builtin_memcpy(&uh.y, &h23, 4);
    __builtin_memcpy(&ul.x, &l01, 4);
    __builtin_memcpy(&ul.y, &l23, 4);
    *(uint2*)((char*)&zh[b][w][nt][tl] + boff) = uh;
    *(uint2*)((char*)&zl[b][w][nt][tl] + boff) = ul;
  };

  #pragma unroll
  for (int mt = 0; mt < 2; ++mt)
    #pragma unroll
    for (int nt = 0; nt < 4; ++nt) emit_chunk(0, mt, nt);
  __syncthreads();

  for (int step = 0; step < TMAXS; ++step) {
    const int rb = step & 1, wb = rb ^ 1;
    // ---- two nt-pair groups; each: GEMM (4 chains, dep distance 4) then tail ----
    #pragma unroll
    for (int np = 0; np < 2; ++np) {
      f32x4 acc[2][2] = {};                 // [mt][nj], nt = 2*np+nj
      #pragma unroll
      for (int kc = 0; kc < 8; ++kc) {
        f16x8 b0h = zh[rb][kc][2*np+0][l];
        f16x8 b1h = zh[rb][kc][2*np+1][l];
        f16x8 b0l = zl[rb][kc][2*np+0][l];
        f16x8 b1l = zl[rb][kc][2*np+1][l];
        acc[0][0] = __builtin_amdgcn_mfma_f32_16x16x32_f16(ahf[0][kc], b0h, acc[0][0], 0, 0, 0);
        acc[1][0] = __builtin_amdgcn_mfma_f32_16x16x32_f16(ahf[1][kc], b0h, acc[1][0], 0, 0, 0);
        acc[0][1] = __builtin_amdgcn_mfma_f32_16x16x32_f16(ahf[0][kc], b1h, acc[0][1], 0, 0, 0);
        acc[1][1] = __builtin_amdgcn_mfma_f32_16x16x32_f16(ahf[1][kc], b1h, acc[1][1], 0, 0, 0);
        acc[0][0] = __builtin_amdgcn_mfma_f32_16x16x32_f16(ahf[0][kc], b0l, acc[0][0], 0, 0, 0);
        acc[1][0] = __builtin_amdgcn_mfma_f32_16x16x32_f16(ahf[1][kc], b0l, acc[1][0], 0, 0, 0);
        acc[0][1] = __builtin_amdgcn_mfma_f32_16x16x32_f16(ahf[0][kc], b1l, acc[0][1], 0, 0, 0);
        acc[1][1] = __builtin_amdgcn_mfma_f32_16x16x32_f16(ahf[1][kc], b1l, acc[1][1], 0, 0, 0);
        acc[0][0] = __builtin_amdgcn_mfma_f32_16x16x32_f16(alf[0][kc], b0h, acc[0][0], 0, 0, 0);
        acc[1][0] = __builtin_amdgcn_mfma_f32_16x16x32_f16(alf[1][kc], b0h, acc[1][0], 0, 0, 0);
        acc[0][1] = __builtin_amdgcn_mfma_f32_16x16x32_f16(alf[0][kc], b1h, acc[0][1], 0, 0, 0);
        acc[1][1] = __builtin_amdgcn_mfma_f32_16x16x32_f16(alf[1][kc], b1h, acc[1][1], 0, 0, 0);
      }
      // ---- pointwise + emit for these 4 chains (overlaps next group's GEMM) ----
      #pragma unroll
      for (int mt = 0; mt < 2; ++mt)
        #pragma unroll
        for (int nj = 0; nj < 2; ++nj) {
          const int nt = 2*np + nj;
          #pragma unroll
          for (int r = 0; r < 4; ++r) {
            float xc = xr[mt][nt][r];
            float xn = xc + DTS*(c4g*(a2*xc - xc*xc*xc)) + dtb*acc[mt][nj][r];
            xr[mt][nt][r] = fminf(fmaxf(xn, -lim), lim);
          }
          emit_chunk(wb, mt, nt);
        }
    }
    __syncthreads();
  }

  // ---- store result ----
  #pragma unroll
  for (int mt = 0; mt < 2; ++mt)
    #pragma unroll
    for (int nt = 0; nt < 4; ++nt) {
      const int row = rbase + nt*16 + lr;
      const int col = w*32 + mt*16 + lg*4;
      *(f32x4*)&out[row*NDIM + col] = xr[mt][nt];
    }
}

extern "C" void kernel_launch(void* const* d_in, const int* in_sizes, int n_in,
                              void* d_out, int out_size, void* d_ws, size_t ws_size,
                              hipStream_t stream) {
  const float* x  = (const float*)d_in[0];
  const float* bt = (const float*)d_in[1];
  const float* bf = (const float*)d_in[2];
  const float* av = (const float*)d_in[3];
  const float* gm = (const float*)d_in[4];
  float* out = (float*)d_out;
  const int Brows = in_sizes[0] / NDIM;   // 16384

  // workspace layout
  float*  base = (float*)d_ws;                    // 65536 f
  float*  eig  = base + NDIM*NDIM;                // 256 f
  double* Xd   = (double*)(eig + NDIM);           // 8B aligned
  double* Xe   = Xd + NDIM*NDIM;
  double* Td   = Xe + NDIM*NDIM;
  double* StG  = Td + NDIM*NDIM;                  // 2460 -> pad 2560
  double* Rm   = StG + 2560;
  _Float16* Aph = (_Float16*)(Rm + 2560);         // 65536 halves = 128 KB
  _Float16* Apl = Aph + NDIM*NDIM;                // 128 KB

  k_prep <<<NDIM, NDIM, 0, stream>>>(bt, bf, av, gm, base, eig);
  k_stgR <<<KD,   NDIM, 0, stream>>>(base, StG, Rm);
  k_m10x2<<<1,    NDIM, 0, stream>>>(base, Rm, Xd);
  k_x1   <<<NDIM, NDIM, 0, stream>>>(base, StG, Xd);
  // 1 Newton-Schulz polish iteration (fp64): 1e-6 -> 1e-12
  k_T <<<NDIM, NDIM, 0, stream>>>(base, Xd, Td);
  k_XT<<<NDIM, NDIM, 0, stream>>>(Xd, Td, Xe);

  k_Afrag<<<NDIM, NDIM, 0, stream>>>(base, eig, Xe, Aph, Apl);

  k_evolve<<<Brows/64, 512, 0, stream>>>(x, (const f16x8*)Aph, (const f16x8*)Apl, gm, out);
}